// Round 4
// baseline (2406.476 us; speedup 1.0000x reference)
//
#include <hip/hip_runtime.h>
#include <stdint.h>

typedef unsigned short u16;
typedef unsigned int u32;
typedef _Float16 f16;
typedef __attribute__((ext_vector_type(8))) _Float16 f16x8;
typedef __attribute__((ext_vector_type(4))) float f32x4;
typedef __attribute__((ext_vector_type(4))) unsigned short u16x4;
typedef __attribute__((ext_vector_type(4))) unsigned int u32x4;

#define T_SEQ  256
#define BATCH  32
#define DIM    768
#define HID    768
#define G3     2304
#define N_ALL  4608
#define NSLICE 48
#define NBLK   96

__device__ __forceinline__ u16 f2h(float f) {
  return __builtin_bit_cast(u16, (f16)f);
}
__device__ __forceinline__ float h2f(u16 h) {
  return (float)__builtin_bit_cast(f16, h);
}

// L2-bypass (coherent at memory-side cache) ops. sc0 sc1 skips the stale
// per-XCD L2 on both producer and consumer sides; no fences needed.
__device__ __forceinline__ u32x4 ld_coh4(const u32* p) {
  u32x4 v;
  asm volatile("global_load_dwordx4 %0, %1, off sc0 sc1" : "=v"(v) : "v"(p));
  return v;
}
__device__ __forceinline__ void st_coh1(u32* p, u32 v) {
  asm volatile("global_store_dword %0, %1, off sc0 sc1" :: "v"(p), "v"(v));
}
__device__ __forceinline__ void wait_vm0() {
  asm volatile("s_waitcnt vmcnt(0)" ::: "memory");
}
// pack low halves of two tagged words -> one u32 of two f16
__device__ __forceinline__ u32 pk(u32 lo, u32 hi) {
  return __builtin_amdgcn_perm(hi, lo, 0x05040100u);
}

// ---------- f32 -> f16 convert (vectorized) ----------
__global__ void k_cvt(const float* __restrict__ in, u16* __restrict__ out, int n4) {
  int i = blockIdx.x * blockDim.x + threadIdx.x;
  if (i >= n4) return;
  float4 v = ((const float4*)in)[i];
  u16x4 o;
  o[0] = f2h(v.x); o[1] = f2h(v.y); o[2] = f2h(v.z); o[3] = f2h(v.w);
  ((u16x4*)out)[i] = o;
}

// ---------- gx[m][n] = sum_k X[m][k]*W[n][k] + bias[n], stored f16 ----------
__global__ __launch_bounds__(256) void k_gemm(
    const u16* __restrict__ A, const u16* __restrict__ Bw,
    const float* __restrict__ bihf, const float* __restrict__ bihb,
    u16* __restrict__ gx)
{
  __shared__ __align__(16) u16 As[128 * 32];
  __shared__ __align__(16) u16 Bs[128 * 32];
  const int tid  = threadIdx.x;
  const int lane = tid & 63, wave = tid >> 6;
  const int wm = wave >> 1, wn = wave & 1;
  const int m0 = blockIdx.y * 128;
  const int n0 = blockIdx.x * 128;
  const int lr = lane & 15, lk = lane >> 4;
  f32x4 acc[4][4] = {};
  for (int k0 = 0; k0 < DIM; k0 += 32) {
    __syncthreads();
    #pragma unroll
    for (int i = 0; i < 2; ++i) {
      int c = i * 256 + tid;
      int row = c >> 2, kk = (c & 3) * 8;
      *(f16x8*)&As[c * 8] = *(const f16x8*)&A [(size_t)(m0 + row) * DIM + k0 + kk];
      *(f16x8*)&Bs[c * 8] = *(const f16x8*)&Bw[(size_t)(n0 + row) * DIM + k0 + kk];
    }
    __syncthreads();
    f16x8 af[4], bfr[4];
    #pragma unroll
    for (int f = 0; f < 4; ++f) {
      af[f]  = *(const f16x8*)&As[(wm * 64 + f * 16 + lr) * 32 + lk * 8];
      bfr[f] = *(const f16x8*)&Bs[(wn * 64 + f * 16 + lr) * 32 + lk * 8];
    }
    #pragma unroll
    for (int fm = 0; fm < 4; ++fm)
      #pragma unroll
      for (int fn = 0; fn < 4; ++fn)
        acc[fm][fn] = __builtin_amdgcn_mfma_f32_16x16x32_f16(af[fm], bfr[fn], acc[fm][fn], 0, 0, 0);
  }
  #pragma unroll
  for (int fm = 0; fm < 4; ++fm)
    #pragma unroll
    for (int fn = 0; fn < 4; ++fn) {
      int n = n0 + wn * 64 + fn * 16 + lr;
      float bias = (n < G3) ? bihf[n] : bihb[n - G3];
      #pragma unroll
      for (int r = 0; r < 4; ++r) {
        int m = m0 + wm * 64 + fm * 16 + lk * 4 + r;
        gx[(size_t)m * N_ALL + n] = f2h(acc[fm][fn][r] + bias);
      }
    }
}

// ---------- persistent bidirectional GRU scan, tag-embedded exchange ----------
// 96 blocks: dir = blk/48, slice of 16 hidden cols = blk%48. 4 waves split K=768.
// hb: u32 [2 parity][2 dir][32 b][768 c], word = (tag<<16)|f16(h).
// Step s consumes tag s+1 from buf[s&1]; publishes tag s+2 into buf[(s+1)&1].
// No flags, no fences: consumers poll their own data until fresh.
__global__ __launch_bounds__(256, 1) void k_gru(
    const u16* __restrict__ whh,   // [4608][768] f16
    const u16* __restrict__ gx,    // [8192][4608] f16 (includes bih)
    const float* __restrict__ h0,
    const float* __restrict__ bhhf, const float* __restrict__ bhhb,
    const int* __restrict__ lengths,
    u32* __restrict__ hb,
    float* __restrict__ out)
{
  const int blk   = blockIdx.x;
  const int dir   = blk / NSLICE;
  const int slice = blk % NSLICE;
  const int hbase = slice * 16;
  const int tid = threadIdx.x, lane = tid & 63, wave = tid >> 6;
  const int lr = lane & 15, lk = lane >> 4;
  const int c = hbase + lr;
  // parity-double-buffered partials: [par][wave][m][g][lane][4+pad]
  __shared__ float part[2][4][2][3][64][5];

  // Whh B-fragments, register-resident for the whole scan.
  f16x8 bw[3][6];
  #pragma unroll
  for (int g = 0; g < 3; ++g)
    #pragma unroll
    for (int ks = 0; ks < 6; ++ks)
      bw[g][ks] = *(const f16x8*)&whh[(size_t)(dir * G3 + g * HID + hbase + lr) * HID
                                      + wave * 192 + ks * 32 + lk * 8];

  const int m = wave;               // epilogue wave w handles batch half m=w (w<2)
  float hst[4];
  float bh[3] = {0.f, 0.f, 0.f};
  int lenv[4];
  u16 g0[4], g1[4], g2[4];
  if (wave < 2) {
    const float* bhp = dir ? bhhb : bhhf;
    #pragma unroll
    for (int g = 0; g < 3; ++g) bh[g] = bhp[g * HID + c];
    u32* dst0 = hb + (size_t)(0 * 2 + dir) * BATCH * HID;
    #pragma unroll
    for (int r = 0; r < 4; ++r) {
      int b = m * 16 + lk * 4 + r;
      float h = h0[(size_t)dir * BATCH * HID + (size_t)b * HID + c];
      hst[r] = h;
      lenv[r] = lengths[b];
      st_coh1(&dst0[(size_t)b * HID + c], (1u << 16) | (u32)f2h(h));
    }
    int t0 = dir ? (T_SEQ - 1) : 0;
    #pragma unroll
    for (int r = 0; r < 4; ++r) {
      int b = m * 16 + lk * 4 + r;
      size_t off = ((size_t)t0 * BATCH + b) * N_ALL + dir * G3 + c;
      g0[r] = gx[off]; g1[r] = gx[off + HID]; g2[r] = gx[off + 2 * HID];
    }
  }

  for (int s = 0; s < T_SEQ; ++s) {
    const int par = s & 1;
    const int t = dir ? (T_SEQ - 1 - s) : s;
    const u32* src = hb + (size_t)(par * 2 + dir) * BATCH * HID;
    const u32 want = (u32)(s + 1) << 16;
    // ---- poll own fragments until all 24 16B-chunks carry tag s+1 ----
    u32x4 raw[12][2];
    u32 stale = 0xFFFFFFu;
    do {
      #pragma unroll
      for (int i = 0; i < 12; ++i)
        #pragma unroll
        for (int hf = 0; hf < 2; ++hf)
          if (stale & (1u << (i * 2 + hf)))
            raw[i][hf] = ld_coh4(src + (size_t)((i / 6) * 16 + lr) * HID
                                 + wave * 192 + (i % 6) * 32 + lk * 8 + hf * 4);
      wait_vm0();
      __builtin_amdgcn_sched_barrier(0);
      u32 ns = 0;
      #pragma unroll
      for (int i = 0; i < 12; ++i)
        #pragma unroll
        for (int hf = 0; hf < 2; ++hf)
          if (stale & (1u << (i * 2 + hf))) {
            u32x4 v = raw[i][hf];
            u32 bad = ((v.x ^ want) | (v.y ^ want) | (v.z ^ want) | (v.w ^ want)) & 0xFFFF0000u;
            if (bad) ns |= 1u << (i * 2 + hf);
          }
      stale = ns;
    } while (__any(stale != 0));
    // ---- unpack tagged words -> f16x8 fragments (one v_perm per word) ----
    f16x8 ah[2][6];
    #pragma unroll
    for (int i = 0; i < 12; ++i) {
      u32x4 lo = raw[i][0], hi = raw[i][1];
      u32x4 pkd;
      pkd.x = pk(lo.x, lo.y); pkd.y = pk(lo.z, lo.w);
      pkd.z = pk(hi.x, hi.y); pkd.w = pk(hi.z, hi.w);
      ah[i / 6][i % 6] = __builtin_bit_cast(f16x8, pkd);
    }
    // ---- MFMA: gh partial for this wave's K-window ----
    f32x4 acc[2][3] = {};
    #pragma unroll
    for (int ks = 0; ks < 6; ++ks)
      #pragma unroll
      for (int m2 = 0; m2 < 2; ++m2)
        #pragma unroll
        for (int g = 0; g < 3; ++g)
          acc[m2][g] = __builtin_amdgcn_mfma_f32_16x16x32_f16(ah[m2][ks], bw[g][ks], acc[m2][g], 0, 0, 0);
    // ---- cross-wave partial exchange (b32 stores, conflict-free [64][5]) ----
    #pragma unroll
    for (int m2 = 0; m2 < 2; ++m2)
      #pragma unroll
      for (int g = 0; g < 3; ++g)
        #pragma unroll
        for (int j = 0; j < 4; ++j)
          part[par][wave][m2][g][lane][j] = acc[m2][g][j];
    __syncthreads();
    if (wave < 2) {
      u32* dst = hb + (size_t)((par ^ 1) * 2 + dir) * BATCH * HID;
      f32x4 gh[3];
      #pragma unroll
      for (int g = 0; g < 3; ++g) {
        f32x4 v = acc[m][g];
        #pragma unroll
        for (int w = 0; w < 4; ++w) {
          if (w == m) continue;
          #pragma unroll
          for (int j = 0; j < 4; ++j) v[j] += part[par][w][m][g][lane][j];
        }
        gh[g] = v;
      }
      float outv[4];
      #pragma unroll
      for (int r = 0; r < 4; ++r) {
        int b = m * 16 + lk * 4 + r;
        float xr = h2f(g0[r]), xz = h2f(g1[r]), xn = h2f(g2[r]);
        float rg = 1.f / (1.f + __expf(-(xr + gh[0][r] + bh[0])));
        float zg = 1.f / (1.f + __expf(-(xz + gh[1][r] + bh[1])));
        float ng = tanhf(xn + rg * (gh[2][r] + bh[2]));
        float hp = hst[r];
        bool msk = t < lenv[r];
        float hn = msk ? ((1.f - zg) * ng + zg * hp) : hp;
        hst[r] = hn;
        outv[r] = msk ? hn : 0.f;
        st_coh1(&dst[(size_t)b * HID + c], ((u32)(s + 2) << 16) | (u32)f2h(hn));
      }
      #pragma unroll
      for (int r = 0; r < 4; ++r) {
        int b = m * 16 + lk * 4 + r;
        __builtin_nontemporal_store(outv[r],
            &out[((size_t)t * BATCH + b) * (2 * HID) + (size_t)dir * HID + c]);
      }
      if (s + 1 < T_SEQ) {
        int t2 = dir ? (T_SEQ - 2 - s) : (s + 1);
        #pragma unroll
        for (int r = 0; r < 4; ++r) {
          int b = m * 16 + lk * 4 + r;
          size_t off = ((size_t)t2 * BATCH + b) * N_ALL + dir * G3 + c;
          g0[r] = gx[off]; g1[r] = gx[off + HID]; g2[r] = gx[off + 2 * HID];
        }
      }
    }
  }
  if (wave < 2) {
    #pragma unroll
    for (int r = 0; r < 4; ++r) {
      int b = m * 16 + lk * 4 + r;
      out[(size_t)T_SEQ * BATCH * 2 * HID + (size_t)dir * BATCH * HID + (size_t)b * HID + c] = hst[r];
    }
  }
}

extern "C" void kernel_launch(void* const* d_in, const int* in_sizes, int n_in,
                              void* d_out, int out_size, void* d_ws, size_t ws_size,
                              hipStream_t stream) {
  const float* x     = (const float*)d_in[0];
  const float* h0    = (const float*)d_in[1];
  const float* wihf  = (const float*)d_in[2];
  const float* whhf  = (const float*)d_in[3];
  const float* bihf  = (const float*)d_in[4];
  const float* bhhf  = (const float*)d_in[5];
  const float* wihb  = (const float*)d_in[6];
  const float* whhb  = (const float*)d_in[7];
  const float* bihb  = (const float*)d_in[8];
  const float* bhhb  = (const float*)d_in[9];
  const int* lengths = (const int*)d_in[10];
  float* out = (float*)d_out;
  char* ws = (char*)d_ws;

  // xh occupies ws+0 (12.5MB) but is dead after k_gemm; hbuf2 (384KB) reuses
  // ws+0, memset AFTER k_gemm in stream order.
  u16* xh    = (u16*)(ws + 0);            // 12,582,912 B (dead after k_gemm)
  u32* hbuf2 = (u32*)(ws + 0);            //    393,216 B (alive in k_gru)
  u16* wih_h = (u16*)(ws + 12582912);     //  7,077,888 B
  u16* whh_h = (u16*)(ws + 19660800);     //  7,077,888 B
  u16* gx    = (u16*)(ws + 26738688);     // 75,497,472 B

  k_cvt<<<6144, 256, 0, stream>>>(x, xh, 1572864);
  k_cvt<<<1728, 256, 0, stream>>>(wihf, wih_h,            442368);
  k_cvt<<<1728, 256, 0, stream>>>(wihb, wih_h + 1769472,  442368);
  k_cvt<<<1728, 256, 0, stream>>>(whhf, whh_h,            442368);
  k_cvt<<<1728, 256, 0, stream>>>(whhb, whh_h + 1769472,  442368);
  k_gemm<<<dim3(36, 64), 256, 0, stream>>>(xh, wih_h, bihf, bihb, gx);
  hipMemsetAsync(hbuf2, 0, 2 * 2 * BATCH * HID * sizeof(u32), stream);
  k_gru<<<NBLK, 256, 0, stream>>>(whh_h, gx, h0, bhhf, bhhb, lengths, hbuf2, out);
}

// Round 8
// 1768.757 us; speedup vs baseline: 1.3605x; 1.3605x over previous
//
#include <hip/hip_runtime.h>
#include <stdint.h>

typedef unsigned short u16;
typedef unsigned int u32;
typedef _Float16 f16;
typedef __attribute__((ext_vector_type(2))) __fp16 h16x2;
typedef __attribute__((ext_vector_type(8))) _Float16 f16x8;
typedef __attribute__((ext_vector_type(4))) float f32x4;
typedef __attribute__((ext_vector_type(4))) unsigned short u16x4;
typedef __attribute__((ext_vector_type(4))) unsigned int u32x4;

#define T_SEQ  256
#define BATCH  32
#define DIM    768
#define HID    768
#define G3     2304
#define N_ALL  4608
#define NSLICE 48
#define NBLK   96
#define FLAG_STRIDE 32   // u32s; 128B per flag slot

__device__ __forceinline__ u16 f2h(float f) {
  return __builtin_bit_cast(u16, (f16)f);
}
__device__ __forceinline__ float h2f(u16 h) {
  return (float)__builtin_bit_cast(f16, h);
}

// L2-bypass (coherent at memory-side cache) ops; sc0 sc1 on both sides, no fences.
__device__ __forceinline__ f16x8 load_coh16(const u16* p) {
  f16x8 v;
  asm volatile("global_load_dwordx4 %0, %1, off sc0 sc1" : "=v"(v) : "v"(p));
  return v;
}
__device__ __forceinline__ void store_coh16(u16* p, f16x8 v) {
  asm volatile("global_store_dwordx4 %0, %1, off sc0 sc1" :: "v"(p), "v"(v));
}
__device__ __forceinline__ void wait_vm0() {
  asm volatile("s_waitcnt vmcnt(0)" ::: "memory");
}
__device__ __forceinline__ u32 pkrtz(float a, float b) {
  h16x2 p = __builtin_amdgcn_cvt_pkrtz(a, b);
  return __builtin_bit_cast(u32, p);
}
__device__ __forceinline__ f16x8 cvt8(float4 a, float4 b) {
  u32x4 r;
  r.x = pkrtz(a.x, a.y);
  r.y = pkrtz(a.z, a.w);
  r.z = pkrtz(b.x, b.y);
  r.w = pkrtz(b.z, b.w);
  return __builtin_bit_cast(f16x8, r);
}

// ---------- f32 -> f16 convert (for Whh only) ----------
__global__ void k_cvt(const float* __restrict__ in, u16* __restrict__ out, int n4) {
  int i = blockIdx.x * blockDim.x + threadIdx.x;
  if (i >= n4) return;
  float4 v = ((const float4*)in)[i];
  u16x4 o;
  o[0] = f2h(v.x); o[1] = f2h(v.y); o[2] = f2h(v.z); o[3] = f2h(v.w);
  ((u16x4*)out)[i] = o;
}

// ---------- gx = X*Wih^T + bih, f32 inputs converted inline, f16 out ----------
__global__ __launch_bounds__(256) void k_gemm(
    const float* __restrict__ X, const float* __restrict__ Wf,
    const float* __restrict__ Wb,
    const float* __restrict__ bihf, const float* __restrict__ bihb,
    u16* __restrict__ gx)
{
  __shared__ __align__(16) u16 As[128 * 32];
  __shared__ __align__(16) u16 Bs[128 * 32];
  const int tid  = threadIdx.x;
  const int lane = tid & 63, wave = tid >> 6;
  const int wm = wave >> 1, wn = wave & 1;
  const int m0 = blockIdx.y * 128;
  const int n0 = blockIdx.x * 128;
  const int lr = lane & 15, lk = lane >> 4;
  f32x4 acc[4][4] = {};
  for (int k0 = 0; k0 < DIM; k0 += 32) {
    __syncthreads();
    #pragma unroll
    for (int i = 0; i < 2; ++i) {
      int cidx = i * 256 + tid;
      int row = cidx >> 2, kk = (cidx & 3) * 8;
      const float* ap = &X[(size_t)(m0 + row) * DIM + k0 + kk];
      *(f16x8*)&As[cidx * 8] = cvt8(*(const float4*)ap, *(const float4*)(ap + 4));
      int n = n0 + row;
      const float* bp = (n < G3 ? &Wf[(size_t)n * DIM] : &Wb[(size_t)(n - G3) * DIM]) + k0 + kk;
      *(f16x8*)&Bs[cidx * 8] = cvt8(*(const float4*)bp, *(const float4*)(bp + 4));
    }
    __syncthreads();
    f16x8 af[4], bfr[4];
    #pragma unroll
    for (int f = 0; f < 4; ++f) {
      af[f]  = *(const f16x8*)&As[(wm * 64 + f * 16 + lr) * 32 + lk * 8];
      bfr[f] = *(const f16x8*)&Bs[(wn * 64 + f * 16 + lr) * 32 + lk * 8];
    }
    #pragma unroll
    for (int fm = 0; fm < 4; ++fm)
      #pragma unroll
      for (int fn = 0; fn < 4; ++fn)
        acc[fm][fn] = __builtin_amdgcn_mfma_f32_16x16x32_f16(af[fm], bfr[fn], acc[fm][fn], 0, 0, 0);
  }
  #pragma unroll
  for (int fm = 0; fm < 4; ++fm)
    #pragma unroll
    for (int fn = 0; fn < 4; ++fn) {
      int n = n0 + wn * 64 + fn * 16 + lr;
      float bias = (n < G3) ? bihf[n] : bihb[n - G3];
      #pragma unroll
      for (int r = 0; r < 4; ++r) {
        int m = m0 + wm * 64 + fm * 16 + lk * 4 + r;
        gx[(size_t)m * N_ALL + n] = f2h(acc[fm][fn][r] + bias);
      }
    }
}

// ---------- persistent bidirectional GRU scan (r3 flag protocol, tuned) ----------
// 96 blocks: dir = blk/48, slice of 16 hidden cols = blk%48. 4 waves split K=768.
// hbuf: f16 [2 par][2 dir][32][768]. Waves 0,1 each own 16 batch rows: compute
// gates, publish own rows (b128 burst), vmcnt(0), own flag word. Waves 2,3:
// stage next-step gx into LDS, then poll all 96 flag words of own direction.
__global__ __launch_bounds__(256, 1) void k_gru(
    const u16* __restrict__ whh,   // [4608][768] f16
    const u16* __restrict__ gx,    // [8192][4608] f16 (includes bih)
    const float* __restrict__ h0,
    const float* __restrict__ bhhf, const float* __restrict__ bhhb,
    const int* __restrict__ lengths,
    u16* __restrict__ hbuf,
    float* __restrict__ out, int* __restrict__ flags)
{
  const int blk   = blockIdx.x;
  const int dir   = blk / NSLICE;
  const int slice = blk % NSLICE;
  const int hbase = slice * 16;
  const int tid = threadIdx.x, lane = tid & 63, wave = tid >> 6;
  const int lr = lane & 15, lk = lane >> 4;
  const int c = hbase + lr;
  const int p = tid - 128;               // waves 2,3 -> pollers 0..95 (+32 idle)
  const int widx = (p >= 0 && p < 96) ? ((dir * NSLICE + (p >> 1)) * 2 + (p & 1)) : 0;

  __shared__ __align__(16) f32x4 part[4][2][3][64];  // 24576 B
  __shared__ __align__(16) u16 gxl[2][3][32][16];    //  6144 B
  __shared__ __align__(16) u16 hx[32][16];           //  1024 B

  // Whh B-fragments, register-resident for the whole scan.
  f16x8 bw[3][6];
  #pragma unroll
  for (int g = 0; g < 3; ++g)
    #pragma unroll
    for (int ks = 0; ks < 6; ++ks)
      bw[g][ks] = *(const f16x8*)&whh[(size_t)(dir * G3 + g * HID + hbase + lr) * HID
                                      + wave * 192 + ks * 32 + lk * 8];

  const int m = wave;                // epilogue wave w handles batch half m=w (w<2)
  float hst[4];
  float bh[3] = {0.f, 0.f, 0.f};
  int lenv[4];
  if (wave < 2) {
    const float* bhp = dir ? bhhb : bhhf;
    #pragma unroll
    for (int g = 0; g < 3; ++g) bh[g] = bhp[g * HID + c];
    #pragma unroll
    for (int r = 0; r < 4; ++r) {
      int b = m * 16 + lk * 4 + r;
      float h = h0[(size_t)dir * BATCH * HID + (size_t)b * HID + c];
      hst[r] = h;
      lenv[r] = lengths[b];
      hx[b][lr] = f2h(h);
    }
    // publish own 16 rows of h0 into parity 0 (coalesced 16B per lane, 32 lanes)
    u16* dst0 = hbuf + (size_t)(0 * 2 + dir) * BATCH * HID;
    if (lane < 32) {
      int row = m * 16 + (lane >> 1), col8 = (lane & 1) * 8;
      f16x8 hv = *(const f16x8*)&hx[row][col8];
      store_coh16(&dst0[(size_t)row * HID + hbase + col8], hv);
    }
    wait_vm0();
    if (lane == 0)
      __hip_atomic_store(&flags[(blk * 2 + wave) * FLAG_STRIDE], 1,
                         __ATOMIC_RELAXED, __HIP_MEMORY_SCOPE_AGENT);
  } else {
    // initial gx slice for t(0) -> gxl[0]
    int t0 = dir ? (T_SEQ - 1) : 0;
    int idx = (wave - 2) * 64 + lane;     // 0..127
    int cc = idx & 15, bq = idx >> 4;     // 16 cols x 8 row-quads
    #pragma unroll
    for (int g = 0; g < 3; ++g)
      #pragma unroll
      for (int j = 0; j < 4; ++j) {
        int b = bq * 4 + j;
        gxl[0][g][b][cc] = gx[((size_t)t0 * BATCH + b) * N_ALL + dir * G3 + g * HID + hbase + cc];
      }
    if (p >= 0 && p < 96) {
      while (__hip_atomic_load(&flags[widx * FLAG_STRIDE], __ATOMIC_RELAXED,
                               __HIP_MEMORY_SCOPE_AGENT) < 1)
        __builtin_amdgcn_s_sleep(1);
    }
  }
  __syncthreads();

  for (int s = 0; s < T_SEQ; ++s) {
    const int par = s & 1;
    const int t = dir ? (T_SEQ - 1 - s) : s;
    const u16* hb = hbuf + (size_t)(par * 2 + dir) * BATCH * HID;
    f16x8 ah[2][6];
    #pragma unroll
    for (int m2 = 0; m2 < 2; ++m2)
      #pragma unroll
      for (int ks = 0; ks < 6; ++ks)
        ah[m2][ks] = load_coh16(&hb[(size_t)(m2 * 16 + lr) * HID + wave * 192 + ks * 32 + lk * 8]);
    wait_vm0();
    __builtin_amdgcn_sched_barrier(0);
    f32x4 acc[2][3] = {};
    #pragma unroll
    for (int ks = 0; ks < 6; ++ks)
      #pragma unroll
      for (int m2 = 0; m2 < 2; ++m2)
        #pragma unroll
        for (int g = 0; g < 3; ++g)
          acc[m2][g] = __builtin_amdgcn_mfma_f32_16x16x32_f16(ah[m2][ks], bw[g][ks], acc[m2][g], 0, 0, 0);
    #pragma unroll
    for (int m2 = 0; m2 < 2; ++m2)
      #pragma unroll
      for (int g = 0; g < 3; ++g)
        part[wave][m2][g][lane] = acc[m2][g];
    __syncthreads();                       // mid barrier
    if (wave < 2) {
      u16* dst = hbuf + (size_t)((par ^ 1) * 2 + dir) * BATCH * HID;
      f32x4 gh[3];
      #pragma unroll
      for (int g = 0; g < 3; ++g) {
        f32x4 v = acc[m][g];
        #pragma unroll
        for (int w = 0; w < 4; ++w) {
          if (w == m) continue;
          v += part[w][m][g][lane];
        }
        gh[g] = v;
      }
      float outv[4];
      #pragma unroll
      for (int r = 0; r < 4; ++r) {
        int b = m * 16 + lk * 4 + r;
        float xr = h2f(gxl[par][0][b][lr]);
        float xz = h2f(gxl[par][1][b][lr]);
        float xn = h2f(gxl[par][2][b][lr]);
        float rg = 1.f / (1.f + __expf(-(xr + gh[0][r] + bh[0])));
        float zg = 1.f / (1.f + __expf(-(xz + gh[1][r] + bh[1])));
        float e2 = __expf(2.f * (xn + rg * (gh[2][r] + bh[2])));
        float ng = 1.f - 2.f / (e2 + 1.f);
        float hp = hst[r];
        bool msk = t < lenv[r];
        float hn = msk ? ((1.f - zg) * ng + zg * hp) : hp;
        hst[r] = hn;
        outv[r] = msk ? hn : 0.f;
        hx[b][lr] = f2h(hn);
      }
      // publish own rows (16B x 32 lanes), ack, own flag
      if (lane < 32) {
        int row = m * 16 + (lane >> 1), col8 = (lane & 1) * 8;
        f16x8 hv = *(const f16x8*)&hx[row][col8];
        store_coh16(&dst[(size_t)row * HID + hbase + col8], hv);
      }
      wait_vm0();
      if (lane == 0)
        __hip_atomic_store(&flags[(blk * 2 + wave) * FLAG_STRIDE], s + 2,
                           __ATOMIC_RELAXED, __HIP_MEMORY_SCOPE_AGENT);
      // off the critical path: out stores
      #pragma unroll
      for (int r = 0; r < 4; ++r) {
        int b = m * 16 + lk * 4 + r;
        __builtin_nontemporal_store(outv[r],
            &out[((size_t)t * BATCH + b) * (2 * HID) + (size_t)dir * HID + c]);
      }
    } else {
      // stage next-step gx into gxl (overlapped with epilogue + flag latency)
      if (s + 1 < T_SEQ) {
        int t2 = dir ? (T_SEQ - 2 - s) : (s + 1);
        int idx = (wave - 2) * 64 + lane;
        int cc = idx & 15, bq = idx >> 4;
        u16 gpre[12];
        #pragma unroll
        for (int g = 0; g < 3; ++g)
          #pragma unroll
          for (int j = 0; j < 4; ++j)
            gpre[g * 4 + j] = gx[((size_t)t2 * BATCH + bq * 4 + j) * N_ALL
                                 + dir * G3 + g * HID + hbase + cc];
        #pragma unroll
        for (int g = 0; g < 3; ++g)
          #pragma unroll
          for (int j = 0; j < 4; ++j)
            gxl[par ^ 1][g][bq * 4 + j][cc] = gpre[g * 4 + j];
      }
      if (p >= 0 && p < 96) {
        while (__hip_atomic_load(&flags[widx * FLAG_STRIDE], __ATOMIC_RELAXED,
                                 __HIP_MEMORY_SCOPE_AGENT) < s + 2)
          __builtin_amdgcn_s_sleep(1);
      }
    }
    __syncthreads();                       // end barrier
  }
  if (wave < 2) {
    #pragma unroll
    for (int r = 0; r < 4; ++r) {
      int b = m * 16 + lk * 4 + r;
      out[(size_t)T_SEQ * BATCH * 2 * HID + (size_t)dir * BATCH * HID + (size_t)b * HID + c] = hst[r];
    }
  }
}

extern "C" void kernel_launch(void* const* d_in, const int* in_sizes, int n_in,
                              void* d_out, int out_size, void* d_ws, size_t ws_size,
                              hipStream_t stream) {
  const float* x     = (const float*)d_in[0];
  const float* h0    = (const float*)d_in[1];
  const float* wihf  = (const float*)d_in[2];
  const float* whhf  = (const float*)d_in[3];
  const float* bihf  = (const float*)d_in[4];
  const float* bhhf  = (const float*)d_in[5];
  const float* wihb  = (const float*)d_in[6];
  const float* whhb  = (const float*)d_in[7];
  const float* bihb  = (const float*)d_in[8];
  const float* bhhb  = (const float*)d_in[9];
  const int* lengths = (const int*)d_in[10];
  float* out = (float*)d_out;
  char* ws = (char*)d_ws;

  int* flags = (int*)(ws + 0);            //     24,576 B (192 words x 128B)
  u16* whh_h = (u16*)(ws + 24576);        //  7,077,888 B
  u16* hbuf  = (u16*)(ws + 7102464);      //    196,608 B
  u16* gx    = (u16*)(ws + 7299072);      // 75,497,472 B

  k_cvt<<<1728, 256, 0, stream>>>(whhf, whh_h,            442368);
  k_cvt<<<1728, 256, 0, stream>>>(whhb, whh_h + 1769472,  442368);
  (void)hipMemsetAsync(flags, 0, NBLK * 2 * FLAG_STRIDE * sizeof(int), stream);
  k_gemm<<<dim3(36, 64), 256, 0, stream>>>(x, wihf, wihb, bihf, bihb, gx);
  k_gru<<<NBLK, 256, 0, stream>>>(whh_h, gx, h0, bhhf, bhhb, lengths, hbuf, out, flags);
}

// Round 9
// 1763.332 us; speedup vs baseline: 1.3647x; 1.0031x over previous
//
#include <hip/hip_runtime.h>
#include <stdint.h>

typedef unsigned short u16;
typedef unsigned int u32;
typedef _Float16 f16;
typedef __attribute__((ext_vector_type(2))) __fp16 h16x2;
typedef __attribute__((ext_vector_type(8))) _Float16 f16x8;
typedef __attribute__((ext_vector_type(4))) float f32x4;
typedef __attribute__((ext_vector_type(4))) unsigned short u16x4;
typedef __attribute__((ext_vector_type(4))) unsigned int u32x4;

#define T_SEQ  256
#define BATCH  32
#define DIM    768
#define HID    768
#define G3     2304
#define N_ALL  4608
#define NSLICE 48
#define NBLK   96
#define FLAG_STRIDE 32   // ints; 128B per flag slot

__device__ __forceinline__ u16 f2h(float f) {
  return __builtin_bit_cast(u16, (f16)f);
}
__device__ __forceinline__ float h2f(u16 h) {
  return (float)__builtin_bit_cast(f16, h);
}

// L2-bypass (coherent at memory-side cache) ops; sc0 sc1 on both sides, no fences.
__device__ __forceinline__ f16x8 load_coh16(const u16* p) {
  f16x8 v;
  asm volatile("global_load_dwordx4 %0, %1, off sc0 sc1" : "=v"(v) : "v"(p));
  return v;
}
__device__ __forceinline__ void store_coh16(u16* p, f16x8 v) {
  asm volatile("global_store_dwordx4 %0, %1, off sc0 sc1" :: "v"(p), "v"(v));
}
__device__ __forceinline__ void wait_vm0() {
  asm volatile("s_waitcnt vmcnt(0)" ::: "memory");
}
__device__ __forceinline__ u32 pkrtz(float a, float b) {
  h16x2 p = __builtin_amdgcn_cvt_pkrtz(a, b);
  return __builtin_bit_cast(u32, p);
}
__device__ __forceinline__ f16x8 cvt8(float4 a, float4 b) {
  u32x4 r;
  r.x = pkrtz(a.x, a.y);
  r.y = pkrtz(a.z, a.w);
  r.z = pkrtz(b.x, b.y);
  r.w = pkrtz(b.z, b.w);
  return __builtin_bit_cast(f16x8, r);
}

// ---------- f32 -> f16 convert (for Whh only) ----------
__global__ void k_cvt(const float* __restrict__ in, u16* __restrict__ out, int n4) {
  int i = blockIdx.x * blockDim.x + threadIdx.x;
  if (i >= n4) return;
  float4 v = ((const float4*)in)[i];
  u16x4 o;
  o[0] = f2h(v.x); o[1] = f2h(v.y); o[2] = f2h(v.z); o[3] = f2h(v.w);
  ((u16x4*)out)[i] = o;
}

// ---------- gx = X*Wih^T + bih, f32 inputs converted inline, f16 out ----------
__global__ __launch_bounds__(256) void k_gemm(
    const float* __restrict__ X, const float* __restrict__ Wf,
    const float* __restrict__ Wb,
    const float* __restrict__ bihf, const float* __restrict__ bihb,
    u16* __restrict__ gx)
{
  __shared__ __align__(16) u16 As[128 * 32];
  __shared__ __align__(16) u16 Bs[128 * 32];
  const int tid  = threadIdx.x;
  const int lane = tid & 63, wave = tid >> 6;
  const int wm = wave >> 1, wn = wave & 1;
  const int m0 = blockIdx.y * 128;
  const int n0 = blockIdx.x * 128;
  const int lr = lane & 15, lk = lane >> 4;
  f32x4 acc[4][4] = {};
  for (int k0 = 0; k0 < DIM; k0 += 32) {
    __syncthreads();
    #pragma unroll
    for (int i = 0; i < 2; ++i) {
      int cidx = i * 256 + tid;
      int row = cidx >> 2, kk = (cidx & 3) * 8;
      const float* ap = &X[(size_t)(m0 + row) * DIM + k0 + kk];
      *(f16x8*)&As[cidx * 8] = cvt8(*(const float4*)ap, *(const float4*)(ap + 4));
      int n = n0 + row;
      const float* bp = (n < G3 ? &Wf[(size_t)n * DIM] : &Wb[(size_t)(n - G3) * DIM]) + k0 + kk;
      *(f16x8*)&Bs[cidx * 8] = cvt8(*(const float4*)bp, *(const float4*)(bp + 4));
    }
    __syncthreads();
    f16x8 af[4], bfr[4];
    #pragma unroll
    for (int f = 0; f < 4; ++f) {
      af[f]  = *(const f16x8*)&As[(wm * 64 + f * 16 + lr) * 32 + lk * 8];
      bfr[f] = *(const f16x8*)&Bs[(wn * 64 + f * 16 + lr) * 32 + lk * 8];
    }
    #pragma unroll
    for (int fm = 0; fm < 4; ++fm)
      #pragma unroll
      for (int fn = 0; fn < 4; ++fn)
        acc[fm][fn] = __builtin_amdgcn_mfma_f32_16x16x32_f16(af[fm], bfr[fn], acc[fm][fn], 0, 0, 0);
  }
  #pragma unroll
  for (int fm = 0; fm < 4; ++fm)
    #pragma unroll
    for (int fn = 0; fn < 4; ++fn) {
      int n = n0 + wn * 64 + fn * 16 + lr;
      float bias = (n < G3) ? bihf[n] : bihb[n - G3];
      #pragma unroll
      for (int r = 0; r < 4; ++r) {
        int m = m0 + wm * 64 + fm * 16 + lk * 4 + r;
        gx[(size_t)m * N_ALL + n] = f2h(acc[fm][fn][r] + bias);
      }
    }
}

// ---------- persistent bidirectional GRU scan (r3 protocol, 2-wave epilogue) ----------
// 96 blocks: dir = blk/48, slice of 16 hidden cols = blk%48. 4 waves split K=768.
// Waves 0,1: epilogue for batch half m=wave (reduce, gates, publish own 512B,
// own vm0 ack, own flag; gx prefetch to regs AFTER flag). Waves 2,3: poll-only
// (96 pollers x 1 flag each), fully overlapped with the epilogue.
__global__ __launch_bounds__(256, 1) void k_gru(
    const u16* __restrict__ whh,   // [4608][768] f16
    const u16* __restrict__ gx,    // [8192][4608] f16 (includes bih)
    const float* __restrict__ h0,
    const float* __restrict__ bhhf, const float* __restrict__ bhhb,
    const int* __restrict__ lengths,
    u16* __restrict__ hbuf,        // f16 [2 par][2 dir][32][768]
    float* __restrict__ out, int* __restrict__ flags)
{
  const int blk   = blockIdx.x;
  const int dir   = blk / NSLICE;
  const int slice = blk % NSLICE;
  const int hbase = slice * 16;
  const int tid = threadIdx.x, lane = tid & 63, wave = tid >> 6;
  const int lr = lane & 15, lk = lane >> 4;
  const int c = hbase + lr;
  const int p = tid - 128;               // waves 2,3 -> pollers 0..95 (+32 idle)
  const int widx = (p >= 0 && p < 96) ? ((dir * NSLICE + (p >> 1)) * 2 + (p & 1)) : 0;

  __shared__ __align__(16) f32x4 part[4][2][3][64];  // 24576 B
  __shared__ __align__(16) u16 hx[32][16];           //  1024 B

  // Whh B-fragments, register-resident for the whole scan.
  f16x8 bw[3][6];
  #pragma unroll
  for (int g = 0; g < 3; ++g)
    #pragma unroll
    for (int ks = 0; ks < 6; ++ks)
      bw[g][ks] = *(const f16x8*)&whh[(size_t)(dir * G3 + g * HID + hbase + lr) * HID
                                      + wave * 192 + ks * 32 + lk * 8];

  const int m = wave;                // epilogue wave w handles batch half m=w (w<2)
  float hst[4];
  float bh[3] = {0.f, 0.f, 0.f};
  int lenv[4];
  u16 g0[4], g1[4], g2[4];
  if (wave < 2) {
    const float* bhp = dir ? bhhb : bhhf;
    #pragma unroll
    for (int g = 0; g < 3; ++g) bh[g] = bhp[g * HID + c];
    #pragma unroll
    for (int r = 0; r < 4; ++r) {
      int b = m * 16 + lk * 4 + r;
      float h = h0[(size_t)dir * BATCH * HID + (size_t)b * HID + c];
      hst[r] = h;
      lenv[r] = lengths[b];
      hx[b][lr] = f2h(h);
    }
    // publish own 16 rows of h0 into parity 0 (16B per lane, 32 lanes)
    asm volatile("s_waitcnt lgkmcnt(0)" ::: "memory");
    u16* dst0 = hbuf + (size_t)(0 * 2 + dir) * BATCH * HID;
    if (lane < 32) {
      int row = m * 16 + (lane >> 1), col8 = (lane & 1) * 8;
      f16x8 hv = *(const f16x8*)&hx[row][col8];
      store_coh16(&dst0[(size_t)row * HID + hbase + col8], hv);
    }
    wait_vm0();
    if (lane == 0)
      __hip_atomic_store(&flags[(blk * 2 + wave) * FLAG_STRIDE], 1,
                         __ATOMIC_RELAXED, __HIP_MEMORY_SCOPE_AGENT);
    // prefetch gx for first step (plain cached loads, hidden under poll)
    int t0 = dir ? (T_SEQ - 1) : 0;
    #pragma unroll
    for (int r = 0; r < 4; ++r) {
      int b = m * 16 + lk * 4 + r;
      size_t off = ((size_t)t0 * BATCH + b) * N_ALL + dir * G3 + c;
      g0[r] = gx[off]; g1[r] = gx[off + HID]; g2[r] = gx[off + 2 * HID];
    }
  } else if (p >= 0 && p < 96) {
    while (__hip_atomic_load(&flags[widx * FLAG_STRIDE], __ATOMIC_RELAXED,
                             __HIP_MEMORY_SCOPE_AGENT) < 1)
      __builtin_amdgcn_s_sleep(1);
  }
  __syncthreads();

  for (int s = 0; s < T_SEQ; ++s) {
    const int par = s & 1;
    const int t = dir ? (T_SEQ - 1 - s) : s;
    const u16* hb = hbuf + (size_t)(par * 2 + dir) * BATCH * HID;
    f16x8 ah[2][6];
    #pragma unroll
    for (int m2 = 0; m2 < 2; ++m2)
      #pragma unroll
      for (int ks = 0; ks < 6; ++ks)
        ah[m2][ks] = load_coh16(&hb[(size_t)(m2 * 16 + lr) * HID + wave * 192 + ks * 32 + lk * 8]);
    wait_vm0();
    __builtin_amdgcn_sched_barrier(0);
    f32x4 acc[2][3] = {};
    #pragma unroll
    for (int ks = 0; ks < 6; ++ks)
      #pragma unroll
      for (int m2 = 0; m2 < 2; ++m2)
        #pragma unroll
        for (int g = 0; g < 3; ++g)
          acc[m2][g] = __builtin_amdgcn_mfma_f32_16x16x32_f16(ah[m2][ks], bw[g][ks], acc[m2][g], 0, 0, 0);
    #pragma unroll
    for (int m2 = 0; m2 < 2; ++m2)
      #pragma unroll
      for (int g = 0; g < 3; ++g)
        part[wave][m2][g][lane] = acc[m2][g];
    __syncthreads();                       // mid barrier
    if (wave < 2) {
      u16* dst = hbuf + (size_t)((par ^ 1) * 2 + dir) * BATCH * HID;
      f32x4 gh[3];
      #pragma unroll
      for (int g = 0; g < 3; ++g) {
        f32x4 v = acc[m][g];
        #pragma unroll
        for (int w = 0; w < 4; ++w) {
          if (w == m) continue;
          v += part[w][m][g][lane];
        }
        gh[g] = v;
      }
      float outv[4];
      #pragma unroll
      for (int r = 0; r < 4; ++r) {
        int b = m * 16 + lk * 4 + r;
        float xr = h2f(g0[r]), xz = h2f(g1[r]), xn = h2f(g2[r]);
        float rg = 1.f / (1.f + __expf(-(xr + gh[0][r] + bh[0])));
        float zg = 1.f / (1.f + __expf(-(xz + gh[1][r] + bh[1])));
        float e2 = __expf(2.f * (xn + rg * (gh[2][r] + bh[2])));
        float ng = 1.f - 2.f / (e2 + 1.f);
        float hp = hst[r];
        bool msk = t < lenv[r];
        float hn = msk ? ((1.f - zg) * ng + zg * hp) : hp;
        hst[r] = hn;
        outv[r] = msk ? hn : 0.f;
        hx[b][lr] = f2h(hn);
      }
      // publish own 16 rows (16B x 32 lanes = 512B), ack, own flag
      asm volatile("s_waitcnt lgkmcnt(0)" ::: "memory");
      if (lane < 32) {
        int row = m * 16 + (lane >> 1), col8 = (lane & 1) * 8;
        f16x8 hv = *(const f16x8*)&hx[row][col8];
        store_coh16(&dst[(size_t)row * HID + hbase + col8], hv);
      }
      wait_vm0();
      if (lane == 0)
        __hip_atomic_store(&flags[(blk * 2 + wave) * FLAG_STRIDE], s + 2,
                           __ATOMIC_RELAXED, __HIP_MEMORY_SCOPE_AGENT);
      // off the critical path: out stores + next gx prefetch (cached)
      #pragma unroll
      for (int r = 0; r < 4; ++r) {
        int b = m * 16 + lk * 4 + r;
        __builtin_nontemporal_store(outv[r],
            &out[((size_t)t * BATCH + b) * (2 * HID) + (size_t)dir * HID + c]);
      }
      if (s + 1 < T_SEQ) {
        int t2 = dir ? (T_SEQ - 2 - s) : (s + 1);
        #pragma unroll
        for (int r = 0; r < 4; ++r) {
          int b = m * 16 + lk * 4 + r;
          size_t off = ((size_t)t2 * BATCH + b) * N_ALL + dir * G3 + c;
          g0[r] = gx[off]; g1[r] = gx[off + HID]; g2[r] = gx[off + 2 * HID];
        }
      }
    } else if (p >= 0 && p < 96) {
      while (__hip_atomic_load(&flags[widx * FLAG_STRIDE], __ATOMIC_RELAXED,
                               __HIP_MEMORY_SCOPE_AGENT) < s + 2)
        __builtin_amdgcn_s_sleep(1);
    }
    __syncthreads();                       // end barrier
  }
  if (wave < 2) {
    #pragma unroll
    for (int r = 0; r < 4; ++r) {
      int b = m * 16 + lk * 4 + r;
      out[(size_t)T_SEQ * BATCH * 2 * HID + (size_t)dir * BATCH * HID + (size_t)b * HID + c] = hst[r];
    }
  }
}

extern "C" void kernel_launch(void* const* d_in, const int* in_sizes, int n_in,
                              void* d_out, int out_size, void* d_ws, size_t ws_size,
                              hipStream_t stream) {
  const float* x     = (const float*)d_in[0];
  const float* h0    = (const float*)d_in[1];
  const float* wihf  = (const float*)d_in[2];
  const float* whhf  = (const float*)d_in[3];
  const float* bihf  = (const float*)d_in[4];
  const float* bhhf  = (const float*)d_in[5];
  const float* wihb  = (const float*)d_in[6];
  const float* whhb  = (const float*)d_in[7];
  const float* bihb  = (const float*)d_in[8];
  const float* bhhb  = (const float*)d_in[9];
  const int* lengths = (const int*)d_in[10];
  float* out = (float*)d_out;
  char* ws = (char*)d_ws;

  int* flags = (int*)(ws + 0);            //     24,576 B (192 slots x 128B)
  u16* whh_h = (u16*)(ws + 24576);        //  7,077,888 B
  u16* hbuf  = (u16*)(ws + 7102464);      //    196,608 B
  u16* gx    = (u16*)(ws + 7299072);      // 75,497,472 B

  k_cvt<<<1728, 256, 0, stream>>>(whhf, whh_h,            442368);
  k_cvt<<<1728, 256, 0, stream>>>(whhb, whh_h + 1769472,  442368);
  (void)hipMemsetAsync(flags, 0, NBLK * 2 * FLAG_STRIDE * sizeof(int), stream);
  k_gemm<<<dim3(36, 64), 256, 0, stream>>>(x, wihf, wihb, bihf, bihb, gx);
  k_gru<<<NBLK, 256, 0, stream>>>(whh_h, gx, h0, bhhf, bhhb, lengths, hbuf, out, flags);
}